// Round 1
// baseline (676.197 us; speedup 1.0000x reference)
//
#include <hip/hip_runtime.h>
#include <math.h>

#define BATCH 16384
#define NCLS  8192
#define NTAIL 16

// ws layout: [0, BATCH*4)            p_true  (float[BATCH])
//            [BATCH*4, BATCH*4+64)   tail counts (int[NTAIL])

__global__ void init_kernel(float* __restrict__ out, int* __restrict__ counts) {
    int t = threadIdx.x;
    if (t < NTAIL) counts[t] = 0;
    if (t == 0)    out[0] = 0.0f;
}

// One block (256 threads = 4 waves) per row. Two-pass, register-resident:
// pass A = branch-free max/argmax (no exp), pass B = independent exp sum.
// This removes the loop-carried exp dependency chain and the divergent
// branch of the online-softmax formulation.
__global__ __launch_bounds__(256) void row_kernel(const float* __restrict__ x,
                                                  const int* __restrict__ labels,
                                                  float* __restrict__ p_true,
                                                  int* __restrict__ counts) {
    const int row = blockIdx.x;
    const int t   = threadIdx.x;
    const float4* rowp = (const float4*)(x + (size_t)row * NCLS);

    // Load all 32 elements (8 x float4) into registers; nan_to_num on the fly.
    float4 v[8];
    #pragma unroll
    for (int k = 0; k < 8; ++k) {
        float4 r = rowp[t + k * 256];
        r.x = (r.x == r.x) ? r.x : 0.0f;
        r.y = (r.y == r.y) ? r.y : 0.0f;
        r.z = (r.z == r.z) ? r.z : 0.0f;
        r.w = (r.w == r.w) ? r.w : 0.0f;
        v[k] = r;
    }

    // Pass A: per-thread max/argmax. 4 independent chains (one per float4
    // component); within a chain indices increase with k, so strict '>'
    // keeps the first occurrence. Chains combined with min-index tie-break.
    float mc0 = -INFINITY, mc1 = -INFINITY, mc2 = -INFINITY, mc3 = -INFINITY;
    int   ic0 = 0, ic1 = 0, ic2 = 0, ic3 = 0;
    #pragma unroll
    for (int k = 0; k < 8; ++k) {
        const int c0 = (t + k * 256) * 4;
        if (v[k].x > mc0) { mc0 = v[k].x; ic0 = c0;     }
        if (v[k].y > mc1) { mc1 = v[k].y; ic1 = c0 + 1; }
        if (v[k].z > mc2) { mc2 = v[k].z; ic2 = c0 + 2; }
        if (v[k].w > mc3) { mc3 = v[k].w; ic3 = c0 + 3; }
    }
    float m = mc0; int idx = ic0;
    if (mc1 > m || (mc1 == m && ic1 < idx)) { m = mc1; idx = ic1; }
    if (mc2 > m || (mc2 == m && ic2 < idx)) { m = mc2; idx = ic2; }
    if (mc3 > m || (mc3 == m && ic3 < idx)) { m = mc3; idx = ic3; }

    // Wave(64) butterfly: all lanes converge to wave (m, idx).
    #pragma unroll
    for (int off = 32; off; off >>= 1) {
        float m2 = __shfl_xor(m, off);
        int   i2 = __shfl_xor(idx, off);
        if (m2 > m || (m2 == m && i2 < idx)) { m = m2; idx = i2; }
    }

    __shared__ float sm[4];
    __shared__ int   si[4];
    __shared__ float ssum[4];
    const int wave = t >> 6;
    if ((t & 63) == 0) { sm[wave] = m; si[wave] = idx; }
    __syncthreads();

    // Every thread combines the 4 wave results (uniform, cheap) -> block M.
    float M = sm[0]; int I = si[0];
    #pragma unroll
    for (int w = 1; w < 4; ++w) {
        if (sm[w] > M || (sm[w] == M && si[w] < I)) { M = sm[w]; I = si[w]; }
    }

    // Pass B: sum of exp(x - M). 4 independent accumulators, branch-free;
    // 32 independent exps issue at throughput rate (no dependent chain).
    float s0 = 0.0f, s1 = 0.0f, s2 = 0.0f, s3 = 0.0f;
    #pragma unroll
    for (int k = 0; k < 8; ++k) {
        s0 += __expf(v[k].x - M);
        s1 += __expf(v[k].y - M);
        s2 += __expf(v[k].z - M);
        s3 += __expf(v[k].w - M);
    }
    float s = (s0 + s1) + (s2 + s3);
    #pragma unroll
    for (int off = 32; off; off >>= 1) s += __shfl_xor(s, off);
    if ((t & 63) == 0) ssum[wave] = s;
    __syncthreads();

    if (t == 0) {
        s = ssum[0] + ssum[1] + ssum[2] + ssum[3];
        const int lab = labels[row];
        float xt = x[(size_t)row * NCLS + lab];
        xt = (xt == xt) ? xt : 0.0f;
        p_true[row] = __expf(xt - M) / s;
        if (I >= NCLS - NTAIL) atomicAdd(&counts[I - (NCLS - NTAIL)], 1);
    }
}

__global__ __launch_bounds__(256) void penalty_kernel(const float* __restrict__ p_true,
                                                      const int* __restrict__ labels,
                                                      const int* __restrict__ prev_counts,
                                                      const int* __restrict__ counts,
                                                      float* __restrict__ out) {
    const int i = blockIdx.x * 256 + threadIdx.x;
    const float p = p_true[i];
    const int lab = labels[i];
    float w = 1.0f;
    if (lab >= NCLS - NTAIL) {
        const int prev = prev_counts[lab];
        const int curr = counts[lab - (NCLS - NTAIL)];
        w = (prev > 0 && curr < prev) ? 4.0f
          : (prev > 0 && curr > prev) ? 2.0f
          : 3.0f;
    }
    float pen = -logf(p + 1e-7f) * (1.0f - p) * w;

    #pragma unroll
    for (int off = 32; off; off >>= 1) pen += __shfl_down(pen, off);

    __shared__ float acc[4];
    if ((threadIdx.x & 63) == 0) acc[threadIdx.x >> 6] = pen;
    __syncthreads();
    if (threadIdx.x == 0) {
        const float bs = acc[0] + acc[1] + acc[2] + acc[3];
        atomicAdd(out, bs * (0.1f / (float)BATCH));
    }
}

extern "C" void kernel_launch(void* const* d_in, const int* in_sizes, int n_in,
                              void* d_out, int out_size, void* d_ws, size_t ws_size,
                              hipStream_t stream) {
    const float* x           = (const float*)d_in[0];
    const int*   labels      = (const int*)  d_in[1];
    const int*   prev_counts = (const int*)  d_in[2];
    // d_in[3] (tail_mask) is deterministic: class >= NCLS-NTAIL — recomputed inline.

    float* out    = (float*)d_out;
    float* p_true = (float*)d_ws;
    int*   counts = (int*)((char*)d_ws + BATCH * sizeof(float));

    init_kernel<<<1, 64, 0, stream>>>(out, counts);
    row_kernel<<<BATCH, 256, 0, stream>>>(x, labels, p_true, counts);
    penalty_kernel<<<BATCH / 256, 256, 0, stream>>>(p_true, labels, prev_counts, counts, out);
}